// Round 9
// baseline (595.397 us; speedup 1.0000x reference)
//
#include <hip/hip_runtime.h>

// QRNN forget-mult: h_t = i_t*z_t + f_t*h_{t-1}, T=4096, B=32, H=256, fp32.
// Round 9: single-pass decoupled-lookback scan. R4/R6/R7/R8 showed the
// 2-big-kernel structure is capped (~1.7 TB/s HBM on partial regardless of
// ILP/TLP). This fuses partial+scan+final into one kernel: per tile
// (chunk, channel-slice): sweep1 local scan -> publish (P,H) -> lookback
// fold for exact entering carry -> sweep2 recompute (L3-hot re-read) + write.
// Ticket-based tile assignment makes waits point only at earlier-scheduled
// tiles -> no deadlock even without full co-residency.

constexpr int T   = 4096;
constexpr int CHN = 32 * 256;   // 8192 channels (B*H)
constexpr int C4  = CHN / 4;    // 2048 float4-channels

typedef float v4f __attribute__((ext_vector_type(4)));

__device__ __forceinline__ void fma_step(float4& h, const float4& ft,
                                         const float4& zt, const float4& it) {
  h.x = fmaf(ft.x, h.x, it.x * zt.x);
  h.y = fmaf(ft.y, h.y, it.y * zt.y);
  h.z = fmaf(ft.z, h.z, it.z * zt.z);
  h.w = fmaf(ft.w, h.w, it.w * zt.w);
}
__device__ __forceinline__ float4 fma4v(const float4& a, const float4& x,
                                        const float4& c) {  // a*x + c
  float4 r;
  r.x = fmaf(a.x, x.x, c.x); r.y = fmaf(a.y, x.y, c.y);
  r.z = fmaf(a.z, x.z, c.z); r.w = fmaf(a.w, x.w, c.w);
  return r;
}
__device__ __forceinline__ float4 mul4(const float4& a, const float4& b) {
  return make_float4(a.x * b.x, a.y * b.y, a.z * b.z, a.w * b.w);
}

// status codes: 0 = empty, 1 = aggregate (P,H) ready, 2 = inclusive carry ready
template <int NC>
__global__ __launch_bounds__(256, 2) void qrnn_onepass(
    const float4* __restrict__ f, const float4* __restrict__ z,
    const float4* __restrict__ ig, const float4* __restrict__ hinit,
    float4* __restrict__ out,
    unsigned* __restrict__ ticket, int* __restrict__ status,
    float4* __restrict__ Pagg, float4* __restrict__ Hagg,
    float4* __restrict__ Hincl) {
  constexpr int CL = T / NC;

  __shared__ int s_tile;
  if (threadIdx.x == 0) s_tile = (int)atomicAdd(ticket, 1u);
  __syncthreads();
  const int tile  = s_tile;
  const int chunk = tile >> 3;
  const int b     = tile & 7;
  const int c4    = b * 256 + (int)threadIdx.x;   // global float4-channel

  // ---- sweep 1: local scan from h=0, plus running forget-product ----
  int idx = chunk * CL * C4 + c4;
  float4 h = make_float4(0.f, 0.f, 0.f, 0.f);
  float4 P = make_float4(1.f, 1.f, 1.f, 1.f);
  for (int t = 0; t < CL; ++t) {
    const float4 ft = f[idx];
    const float4 zt = z[idx];
    const float4 it = ig[idx];
    fma_step(h, ft, zt, it);
    P.x *= ft.x; P.y *= ft.y; P.z *= ft.z; P.w *= ft.w;
    idx += C4;
  }

  const int pb = chunk * C4 + c4;
  float4 E;  // hidden state ENTERING this chunk
  if (chunk == 0) {
    E = hinit[c4];
  } else {
    // publish aggregate so successors can fold past us
    Pagg[pb] = P;
    Hagg[pb] = h;
    __threadfence();
    __hip_atomic_store(&status[tile], 1, __ATOMIC_RELEASE,
                       __HIP_MEMORY_SCOPE_AGENT);
    // ---- lookback fold: E = cH + cP * (inclusive of some predecessor) ----
    float4 cP = make_float4(1.f, 1.f, 1.f, 1.f);
    float4 cH = make_float4(0.f, 0.f, 0.f, 0.f);
    int j = chunk - 1;
    for (;;) {
      const int st = __hip_atomic_load(&status[j * 8 + b], __ATOMIC_ACQUIRE,
                                       __HIP_MEMORY_SCOPE_AGENT);
      if (st == 0) { __builtin_amdgcn_s_sleep(1); continue; }
      if (st == 2) {  // predecessor published its inclusive carry
        const float4 Ij = Hincl[j * C4 + c4];
        E = fma4v(cP, Ij, cH);
        break;
      }
      // st == 1: fold this predecessor's aggregate, keep walking back
      const float4 Pj = Pagg[j * C4 + c4];
      const float4 Hj = Hagg[j * C4 + c4];
      cH = fma4v(cP, Hj, cH);
      cP = mul4(cP, Pj);
      if (--j < 0) {
        const float4 h0 = hinit[c4];
        E = fma4v(cP, h0, cH);
        break;
      }
    }
  }

  // publish our inclusive carry for successors
  if (chunk != NC - 1) {
    Hincl[pb] = fma4v(P, E, h);
    __threadfence();
    __hip_atomic_store(&status[tile], 2, __ATOMIC_RELEASE,
                       __HIP_MEMORY_SCOPE_AGENT);
  }

  // ---- sweep 2: recompute from exact carry (slice is L3-hot), write out ----
  idx = chunk * CL * C4 + c4;
  h = E;
  v4f* __restrict__ outv = (v4f*)out;
  for (int t = 0; t < CL; ++t) {
    const float4 ft = f[idx];
    const float4 zt = z[idx];
    const float4 it = ig[idx];
    fma_step(h, ft, zt, it);
    v4f hv = {h.x, h.y, h.z, h.w};
    __builtin_nontemporal_store(hv, &outv[idx]);
    idx += C4;
  }
}

template <int NC>
static void launch_onepass(const float4* f, const float4* z, const float4* ig,
                           const float4* hinit, float4* out, void* ws,
                           hipStream_t stream) {
  // ws layout: [ticket u32][pad][status NC*8 i32] | payload at +8192
  unsigned* ticket = (unsigned*)ws;
  int* status      = (int*)((char*)ws + 16);
  float4* Pagg  = (float4*)((char*)ws + 8192);
  float4* Hagg  = Pagg + (size_t)NC * C4;
  float4* Hincl = Hagg + (size_t)NC * C4;
  hipMemsetAsync(ws, 0, 16 + (size_t)NC * 8 * 4, stream);
  qrnn_onepass<NC><<<dim3(NC * 8), dim3(256), 0, stream>>>(
      f, z, ig, hinit, out, ticket, status, Pagg, Hagg, Hincl);
}

extern "C" void kernel_launch(void* const* d_in, const int* in_sizes, int n_in,
                              void* d_out, int out_size, void* d_ws, size_t ws_size,
                              hipStream_t stream) {
  const float4* f     = (const float4*)d_in[0];
  const float4* z     = (const float4*)d_in[1];
  const float4* ig    = (const float4*)d_in[2];
  const float4* hinit = (const float4*)d_in[3];
  float4* out = (float4*)d_out;

  auto need = [](int nc) { return 8192 + 3ull * nc * C4 * sizeof(float4); };
  if (ws_size >= need(64)) {
    launch_onepass<64>(f, z, ig, hinit, out, d_ws, stream);   // ~6 MiB ws
  } else {
    launch_onepass<16>(f, z, ig, hinit, out, d_ws, stream);   // ~1.5 MiB ws
  }
}

// Round 10
// 210.070 us; speedup vs baseline: 2.8343x; 2.8343x over previous
//
#include <hip/hip_runtime.h>

// QRNN forget-mult: h_t = i_t*z_t + f_t*h_{t-1}, T=4096, B=32, H=256, fp32.
// Round 10: row-streaming chunked scan. Theory: the 117us partial was capped
// at ~1.7 TB/s HBM because each block walked a 4KB column with 32KB stride
// (poor DRAM row locality). Now each block owns WHOLE 32KB timestep rows:
// NC=256 chunks x CL=16 rows, 256 blocks x 1024 threads, dense sequential
// streams per CU. final identical + nontemporal out stores.

constexpr int T   = 4096;
constexpr int CHN = 32 * 256;   // floats per timestep row (8192)
constexpr int C4  = CHN / 4;    // float4 per row (2048)
constexpr int BT  = 1024;       // threads per row-block

typedef float v4f __attribute__((ext_vector_type(4)));

__device__ __forceinline__ void fma_step(float4& h, const float4& ft,
                                         const float4& zt, const float4& it) {
  h.x = fmaf(ft.x, h.x, it.x * zt.x);
  h.y = fmaf(ft.y, h.y, it.y * zt.y);
  h.z = fmaf(ft.z, h.z, it.z * zt.z);
  h.w = fmaf(ft.w, h.w, it.w * zt.w);
}

// ---------------- kernel 1: per-chunk local recurrence + forget product ----------------
// block = chunk; each thread owns float4-columns tid and tid+1024 of the row.
template <int NC>
__global__ __launch_bounds__(BT, 4) void qrnn_partial(
    const float4* __restrict__ f, const float4* __restrict__ z,
    const float4* __restrict__ ig,
    float4* __restrict__ Ps, float4* __restrict__ Hs) {
  constexpr int CL = T / NC;
  static_assert(CL % 2 == 0, "");
  const int tid   = threadIdx.x;
  const int chunk = blockIdx.x;
  int idx = chunk * CL * C4 + tid;
  float4 h0 = make_float4(0.f, 0.f, 0.f, 0.f), h1 = h0;
  float4 P0 = make_float4(1.f, 1.f, 1.f, 1.f), P1 = P0;
  for (int t = 0; t < CL; t += 2) {
    // 12 independent loads covering rows t, t+1 densely across the block
    const float4 fa0 = f[idx],          fb0 = f[idx + 1024];
    const float4 fa1 = f[idx + 2048],   fb1 = f[idx + 3072];
    const float4 za0 = z[idx],          zb0 = z[idx + 1024];
    const float4 za1 = z[idx + 2048],   zb1 = z[idx + 3072];
    const float4 ia0 = ig[idx],         ib0 = ig[idx + 1024];
    const float4 ia1 = ig[idx + 2048],  ib1 = ig[idx + 3072];
    fma_step(h0, fa0, za0, ia0);
    fma_step(h1, fb0, zb0, ib0);
    P0.x *= fa0.x; P0.y *= fa0.y; P0.z *= fa0.z; P0.w *= fa0.w;
    P1.x *= fb0.x; P1.y *= fb0.y; P1.z *= fb0.z; P1.w *= fb0.w;
    fma_step(h0, fa1, za1, ia1);
    fma_step(h1, fb1, zb1, ib1);
    P0.x *= fa1.x; P0.y *= fa1.y; P0.z *= fa1.z; P0.w *= fa1.w;
    P1.x *= fb1.x; P1.y *= fb1.y; P1.z *= fb1.z; P1.w *= fb1.w;
    idx += 2 * C4;
    __syncthreads();   // keep the block's address window dense
  }
  Ps[chunk * C4 + tid]        = P0;
  Ps[chunk * C4 + tid + 1024] = P1;
  Hs[chunk * C4 + tid]        = h0;
  Hs[chunk * C4 + tid + 1024] = h1;
}

// ---------------- kernel 2: sequential scan over chunk summaries ----------------
// After this: Hs[k] = hidden state ENTERING chunk k.
template <int NC>
__global__ __launch_bounds__(256, 2) void qrnn_scan(
    const float4* __restrict__ hinit,
    const float4* __restrict__ Ps, float4* __restrict__ Hs) {
  const int c4 = blockIdx.x * 256 + threadIdx.x;
  float4 carry = hinit[c4];
  constexpr int US = 16;
  static_assert(NC % US == 0, "");
  for (int k0 = 0; k0 < NC; k0 += US) {
    float4 rp[US], rh[US];
#pragma unroll
    for (int u = 0; u < US; ++u) rp[u] = Ps[(k0 + u) * C4 + c4];
#pragma unroll
    for (int u = 0; u < US; ++u) rh[u] = Hs[(k0 + u) * C4 + c4];
#pragma unroll
    for (int u = 0; u < US; ++u) {
      Hs[(k0 + u) * C4 + c4] = carry;
      carry.x = fmaf(rp[u].x, carry.x, rh[u].x);
      carry.y = fmaf(rp[u].y, carry.y, rh[u].y);
      carry.z = fmaf(rp[u].z, carry.z, rh[u].z);
      carry.w = fmaf(rp[u].w, carry.w, rh[u].w);
    }
  }
}

// ---------------- kernel 3: recompute chunk from exact carry, write output ----------------
template <int NC>
__global__ __launch_bounds__(BT, 4) void qrnn_final(
    const float4* __restrict__ f, const float4* __restrict__ z,
    const float4* __restrict__ ig, const float4* __restrict__ Hs,
    float4* __restrict__ out) {
  constexpr int CL = T / NC;
  static_assert(CL % 2 == 0, "");
  const int tid   = threadIdx.x;
  const int chunk = blockIdx.x;
  int idx = chunk * CL * C4 + tid;
  float4 h0 = Hs[chunk * C4 + tid];
  float4 h1 = Hs[chunk * C4 + tid + 1024];
  v4f* __restrict__ outv = (v4f*)out;
  for (int t = 0; t < CL; t += 2) {
    const float4 fa0 = f[idx],          fb0 = f[idx + 1024];
    const float4 fa1 = f[idx + 2048],   fb1 = f[idx + 3072];
    const float4 za0 = z[idx],          zb0 = z[idx + 1024];
    const float4 za1 = z[idx + 2048],   zb1 = z[idx + 3072];
    const float4 ia0 = ig[idx],         ib0 = ig[idx + 1024];
    const float4 ia1 = ig[idx + 2048],  ib1 = ig[idx + 3072];
    fma_step(h0, fa0, za0, ia0);
    fma_step(h1, fb0, zb0, ib0);
    {
      v4f hv0 = {h0.x, h0.y, h0.z, h0.w};
      v4f hv1 = {h1.x, h1.y, h1.z, h1.w};
      __builtin_nontemporal_store(hv0, &outv[idx]);
      __builtin_nontemporal_store(hv1, &outv[idx + 1024]);
    }
    fma_step(h0, fa1, za1, ia1);
    fma_step(h1, fb1, zb1, ib1);
    {
      v4f hv0 = {h0.x, h0.y, h0.z, h0.w};
      v4f hv1 = {h1.x, h1.y, h1.z, h1.w};
      __builtin_nontemporal_store(hv0, &outv[idx + 2048]);
      __builtin_nontemporal_store(hv1, &outv[idx + 3072]);
    }
    idx += 2 * C4;
    __syncthreads();
  }
}

template <int NC>
static void launch_all(const float4* f, const float4* z, const float4* ig,
                       const float4* hinit, float4* out, void* ws,
                       hipStream_t stream) {
  float4* Ps = (float4*)ws;
  float4* Hs = (float4*)((char*)ws + (size_t)NC * CHN * sizeof(float));
  qrnn_partial<NC><<<dim3(NC), dim3(BT), 0, stream>>>(f, z, ig, Ps, Hs);
  qrnn_scan<NC><<<dim3(C4 / 256), dim3(256), 0, stream>>>(hinit, Ps, Hs);
  qrnn_final<NC><<<dim3(NC), dim3(BT), 0, stream>>>(f, z, ig, Hs, out);
}

extern "C" void kernel_launch(void* const* d_in, const int* in_sizes, int n_in,
                              void* d_out, int out_size, void* d_ws, size_t ws_size,
                              hipStream_t stream) {
  const float4* f     = (const float4*)d_in[0];
  const float4* z     = (const float4*)d_in[1];
  const float4* ig    = (const float4*)d_in[2];
  const float4* hinit = (const float4*)d_in[3];
  float4* out = (float4*)d_out;

  auto need = [](int nc) { return 2ull * nc * CHN * sizeof(float); };
  if (ws_size >= need(256)) {
    launch_all<256>(f, z, ig, hinit, out, d_ws, stream);  // 16.8 MB ws (R7 proved fits)
  } else if (ws_size >= need(64)) {
    launch_all<64>(f, z, ig, hinit, out, d_ws, stream);   // fallback: 64 row-blocks
  } else {
    launch_all<16>(f, z, ig, hinit, out, d_ws, stream);
  }
}

// Round 11
// 178.442 us; speedup vs baseline: 3.3366x; 1.1772x over previous
//
#include <hip/hip_runtime.h>

// QRNN forget-mult: h_t = i_t*z_t + f_t*h_{t-1}, T=4096, B=32, H=256, fp32.
// Round 11: R4/R6 structure (best measured) + XCD-banded block swizzle.
// Theory: delivered read BW is capped ~3.4 TB/s for NC*3 spread streams;
// per-XCD L2/EA locality is the untested knob. Map blocks so XCD x owns
// contiguous chunk band [8x, 8x+8) (48 MB window) instead of round-robin
// spread over all 384 MB.

constexpr int T   = 4096;
constexpr int CHN = 32 * 256;   // 8192 channels (B*H)
constexpr int C4  = CHN / 4;    // 2048 float4-channels

typedef float v4f __attribute__((ext_vector_type(4)));

__device__ __forceinline__ void fma_step(float4& h, const float4& ft,
                                         const float4& zt, const float4& it) {
  h.x = fmaf(ft.x, h.x, it.x * zt.x);
  h.y = fmaf(ft.y, h.y, it.y * zt.y);
  h.z = fmaf(ft.z, h.z, it.z * zt.z);
  h.w = fmaf(ft.w, h.w, it.w * zt.w);
}

// bid in [0, NC*8): returns (chunk, col) with XCD banding.
// XCD = bid%8 owns chunks [XCD*NC/8, (XCD+1)*NC/8).
template <int NC>
__device__ __forceinline__ void tile_map(int bid, int& chunk, int& col) {
  constexpr int CPX = NC / 8;          // chunks per XCD
  const int xcd = bid & 7;
  const int m   = bid >> 3;            // [0, NC)
  chunk = xcd * CPX + (m % CPX);
  col   = m / CPX;                     // [0, 8)
}

// ---------------- kernel 1: per-chunk local recurrence + forget product ----------------
template <int NC>
__global__ __launch_bounds__(256) void qrnn_partial(
    const float4* __restrict__ f, const float4* __restrict__ z,
    const float4* __restrict__ ig,
    float4* __restrict__ Ps, float4* __restrict__ Hs) {
  constexpr int CL = T / NC;
  int chunk, col;
  tile_map<NC>(blockIdx.x, chunk, col);
  const int c4 = col * 256 + (int)threadIdx.x;
  int idx = chunk * CL * C4 + c4;
  float4 h = make_float4(0.f, 0.f, 0.f, 0.f);
  float4 P = make_float4(1.f, 1.f, 1.f, 1.f);
  for (int t = 0; t < CL; ++t) {
    const float4 ft = f[idx];
    const float4 zt = z[idx];
    const float4 it = ig[idx];
    fma_step(h, ft, zt, it);
    P.x *= ft.x; P.y *= ft.y; P.z *= ft.z; P.w *= ft.w;
    idx += C4;
  }
  Ps[chunk * C4 + c4] = P;
  Hs[chunk * C4 + c4] = h;
}

// ---------------- kernel 2: sequential scan over chunk summaries ----------------
// After this: Hs[k] = hidden state ENTERING chunk k.
template <int NC>
__global__ __launch_bounds__(256) void qrnn_scan(
    const float4* __restrict__ hinit,
    const float4* __restrict__ Ps, float4* __restrict__ Hs) {
  const int c4 = blockIdx.x * 256 + threadIdx.x;
  float4 carry = hinit[c4];
  constexpr int US = 16;
  static_assert(NC % US == 0, "");
  for (int k0 = 0; k0 < NC; k0 += US) {
    float4 rp[US], rh[US];
#pragma unroll
    for (int u = 0; u < US; ++u) rp[u] = Ps[(k0 + u) * C4 + c4];
#pragma unroll
    for (int u = 0; u < US; ++u) rh[u] = Hs[(k0 + u) * C4 + c4];
#pragma unroll
    for (int u = 0; u < US; ++u) {
      Hs[(k0 + u) * C4 + c4] = carry;
      carry.x = fmaf(rp[u].x, carry.x, rh[u].x);
      carry.y = fmaf(rp[u].y, carry.y, rh[u].y);
      carry.z = fmaf(rp[u].z, carry.z, rh[u].z);
      carry.w = fmaf(rp[u].w, carry.w, rh[u].w);
    }
  }
}

// ---------------- kernel 3: recompute chunk from exact carry, write output ----------------
template <int NC>
__global__ __launch_bounds__(256) void qrnn_final(
    const float4* __restrict__ f, const float4* __restrict__ z,
    const float4* __restrict__ ig, const float4* __restrict__ Hs,
    float4* __restrict__ out) {
  constexpr int CL = T / NC;
  int chunk, col;
  tile_map<NC>(blockIdx.x, chunk, col);
  const int c4 = col * 256 + (int)threadIdx.x;
  int idx = chunk * CL * C4 + c4;
  float4 h = Hs[chunk * C4 + c4];
  v4f* __restrict__ outv = (v4f*)out;
  for (int t = 0; t < CL; ++t) {
    const float4 ft = f[idx];
    const float4 zt = z[idx];
    const float4 it = ig[idx];
    fma_step(h, ft, zt, it);
    v4f hv = {h.x, h.y, h.z, h.w};
    __builtin_nontemporal_store(hv, &outv[idx]);   // out never re-read
    idx += C4;
  }
}

template <int NC>
static void launch_all(const float4* f, const float4* z, const float4* ig,
                       const float4* hinit, float4* out, void* ws,
                       hipStream_t stream) {
  float4* Ps = (float4*)ws;
  float4* Hs = (float4*)((char*)ws + (size_t)NC * CHN * sizeof(float));
  qrnn_partial<NC><<<dim3(NC * 8), dim3(256), 0, stream>>>(f, z, ig, Ps, Hs);
  qrnn_scan<NC><<<dim3(C4 / 256), dim3(256), 0, stream>>>(hinit, Ps, Hs);
  qrnn_final<NC><<<dim3(NC * 8), dim3(256), 0, stream>>>(f, z, ig, Hs, out);
}

extern "C" void kernel_launch(void* const* d_in, const int* in_sizes, int n_in,
                              void* d_out, int out_size, void* d_ws, size_t ws_size,
                              hipStream_t stream) {
  const float4* f     = (const float4*)d_in[0];
  const float4* z     = (const float4*)d_in[1];
  const float4* ig    = (const float4*)d_in[2];
  const float4* hinit = (const float4*)d_in[3];
  float4* out = (float4*)d_out;

  auto need = [](int nc) { return 2ull * nc * CHN * sizeof(float); };
  if (ws_size >= need(64)) {
    launch_all<64>(f, z, ig, hinit, out, d_ws, stream);   // 4 MiB ws
  } else {
    launch_all<16>(f, z, ig, hinit, out, d_ws, stream);   // 1 MiB ws
  }
}